// Round 1
// baseline (715.508 us; speedup 1.0000x reference)
//
#include <hip/hip_runtime.h>

// SSVI loss: one scalar out.
// entries [B,3] i32 | ys [B] f32 | means [3,NCOL,64] f32 | chols [3,NCOL,64] f32
// eps [3,B,32,64] f32.
// Memory-bound: 201 MB eps + ~13 MB gathers -> ~34 us roofline at 6.3 TB/s.

constexpr int kNDim = 3;
constexpr int kNCol = 500000;
constexpr int kRank = 64;
constexpr int kK1   = 32;
constexpr int kB    = 8192;
constexpr float kHalfLog2Pi = 0.9189385332046727f;  // 0.5*log(2*pi)
// loss = -(NUM_TRAIN/B)*batch_expectation + sum(kl)/B
//      = sum_b [ -(100/32)*sum_k lp(b,k) ] + sum(kl)/8192

__global__ __launch_bounds__(256) void ssvi_loss_kernel(
    const int* __restrict__ entries,
    const float* __restrict__ ys,
    const float* __restrict__ means,
    const float* __restrict__ chols,
    const float* __restrict__ eps,
    float* __restrict__ out)
{
    const int b    = blockIdx.x;
    const int tid  = threadIdx.x;
    const int lane = tid & 63;
    const int wave = tid >> 6;
    const int rg   = lane & 15;   // rank group: float4 over ranks 4*rg..4*rg+3
    const int ksub = lane >> 4;   // 0..3: which k within the wave's 4-k slab

    int idx[3];
#pragma unroll
    for (int d = 0; d < kNDim; ++d) idx[d] = entries[b * kNDim + d];

    // Per-thread gather of m and S = L^2 for its 4 ranks, each dim.
    float4 m[3], S[3];
#pragma unroll
    for (int d = 0; d < kNDim; ++d) {
        const float4* mrow = reinterpret_cast<const float4*>(
            means + ((size_t)d * kNCol + idx[d]) * kRank);
        const float4* lrow = reinterpret_cast<const float4*>(
            chols + ((size_t)d * kNCol + idx[d]) * kRank);
        m[d] = mrow[rg];
        float4 L = lrow[rg];
        S[d].x = L.x * L.x; S[d].y = L.y * L.y;
        S[d].z = L.z * L.z; S[d].w = L.w * L.w;
    }

    const float y = ys[b];

    // MC term: each 16-lane group handles one k per iteration; 16 groups/block,
    // 2 iterations -> all 32 k. fs replicated across the 16 lanes after the
    // butterfly, so scale the accumulated lp by 1/16.
    float lp_acc = 0.0f;
#pragma unroll
    for (int i = 0; i < 2; ++i) {
        const int k = wave * 4 + ksub + 16 * i;
        const float4* e0 = reinterpret_cast<const float4*>(
            eps + (((size_t)0 * kB + b) * kK1 + k) * kRank);
        const float4* e1 = reinterpret_cast<const float4*>(
            eps + (((size_t)1 * kB + b) * kK1 + k) * kRank);
        const float4* e2 = reinterpret_cast<const float4*>(
            eps + (((size_t)2 * kB + b) * kK1 + k) * kRank);
        const float4 ea = e0[rg];
        const float4 eb = e1[rg];
        const float4 ec = e2[rg];

        float4 t0, t1, t2;
        t0.x = fmaf(ea.x, S[0].x, m[0].x); t0.y = fmaf(ea.y, S[0].y, m[0].y);
        t0.z = fmaf(ea.z, S[0].z, m[0].z); t0.w = fmaf(ea.w, S[0].w, m[0].w);
        t1.x = fmaf(eb.x, S[1].x, m[1].x); t1.y = fmaf(eb.y, S[1].y, m[1].y);
        t1.z = fmaf(eb.z, S[1].z, m[1].z); t1.w = fmaf(eb.w, S[1].w, m[1].w);
        t2.x = fmaf(ec.x, S[2].x, m[2].x); t2.y = fmaf(ec.y, S[2].y, m[2].y);
        t2.z = fmaf(ec.z, S[2].z, m[2].z); t2.w = fmaf(ec.w, S[2].w, m[2].w);

        float part = (t0.x * t1.x * t2.x + t0.y * t1.y * t2.y) +
                     (t0.z * t1.z * t2.z + t0.w * t1.w * t2.w);
        // Reduce over the 16 lanes of this k-group (ranks 0..63).
        part += __shfl_xor(part, 1, 64);
        part += __shfl_xor(part, 2, 64);
        part += __shfl_xor(part, 4, 64);
        part += __shfl_xor(part, 8, 64);

        const float diff = part - y;
        lp_acc += -0.5f * diff * diff - kHalfLog2Pi;
    }

    float v = -(100.0f / 32.0f) * (lp_acc * (1.0f / 16.0f));

    // KL: only threads 0..15 (they jointly hold all 64 ranks, once).
    if (tid < 16) {
        float klsum = 0.0f;
#pragma unroll
        for (int d = 0; d < kNDim; ++d) {
            const float4 s = S[d];
            const float4 mm = m[d];
            float4 s2;
            s2.x = s.x * s.x; s2.y = s.y * s.y;
            s2.z = s.z * s.z; s2.w = s.w * s.w;
            klsum += 0.5f * (s2.x + mm.x * mm.x - 1.0f - __logf(s2.x));
            klsum += 0.5f * (s2.y + mm.y * mm.y - 1.0f - __logf(s2.y));
            klsum += 0.5f * (s2.z + mm.z * mm.z - 1.0f - __logf(s2.z));
            klsum += 0.5f * (s2.w + mm.w * mm.w - 1.0f - __logf(s2.w));
        }
        v += klsum * (1.0f / 8192.0f);
    }

    // Block reduction: wave butterfly then LDS across 4 waves.
#pragma unroll
    for (int off = 32; off >= 1; off >>= 1) v += __shfl_down(v, off, 64);

    __shared__ float red[4];
    if (lane == 0) red[wave] = v;
    __syncthreads();
    if (tid == 0) {
        atomicAdd(out, (red[0] + red[1]) + (red[2] + red[3]));
    }
}

extern "C" void kernel_launch(void* const* d_in, const int* in_sizes, int n_in,
                              void* d_out, int out_size, void* d_ws, size_t ws_size,
                              hipStream_t stream) {
    const int*   entries = (const int*)d_in[0];
    const float* ys      = (const float*)d_in[1];
    const float* means   = (const float*)d_in[2];
    const float* chols   = (const float*)d_in[3];
    const float* eps     = (const float*)d_in[4];
    float* out = (float*)d_out;

    hipMemsetAsync(out, 0, sizeof(float), stream);
    ssvi_loss_kernel<<<kB, 256, 0, stream>>>(entries, ys, means, chols, eps, out);
}

// Round 2
// 679.191 us; speedup vs baseline: 1.0535x; 1.0535x over previous
//
#include <hip/hip_runtime.h>

// SSVI loss: one scalar out.
// entries [B,3] i32 | ys [B] f32 | means [3,NCOL,64] f32 | chols [3,NCOL,64] f32
// eps [3,B,32,64] f32.
// Memory-bound: 201 MB eps + ~13 MB gathers -> ~34 us kernel roofline at 6.3 TB/s.
// R1: replaced 8192 same-address atomicAdds (L2 serialization tail) with
// per-block partials in d_ws + a one-block reduce kernel.

constexpr int kNDim = 3;
constexpr int kNCol = 500000;
constexpr int kRank = 64;
constexpr int kK1   = 32;
constexpr int kB    = 8192;
constexpr float kHalfLog2Pi = 0.9189385332046727f;  // 0.5*log(2*pi)
// loss = -(NUM_TRAIN/B)*batch_expectation + sum(kl)/B
//      = sum_b [ -(100/32)*sum_k lp(b,k) ] + sum(kl)/8192

__global__ __launch_bounds__(256) void ssvi_partial_kernel(
    const int* __restrict__ entries,
    const float* __restrict__ ys,
    const float* __restrict__ means,
    const float* __restrict__ chols,
    const float* __restrict__ eps,
    float* __restrict__ partials)
{
    const int b    = blockIdx.x;
    const int tid  = threadIdx.x;
    const int lane = tid & 63;
    const int wave = tid >> 6;
    const int rg   = lane & 15;   // rank group: float4 over ranks 4*rg..4*rg+3
    const int ksub = lane >> 4;   // 0..3: which k within the wave's 4-k slab

    int idx[3];
#pragma unroll
    for (int d = 0; d < kNDim; ++d) idx[d] = entries[b * kNDim + d];

    // Per-thread gather of m and S = L^2 for its 4 ranks, each dim.
    float4 m[3], S[3];
#pragma unroll
    for (int d = 0; d < kNDim; ++d) {
        const float4* mrow = reinterpret_cast<const float4*>(
            means + ((size_t)d * kNCol + idx[d]) * kRank);
        const float4* lrow = reinterpret_cast<const float4*>(
            chols + ((size_t)d * kNCol + idx[d]) * kRank);
        m[d] = mrow[rg];
        float4 L = lrow[rg];
        S[d].x = L.x * L.x; S[d].y = L.y * L.y;
        S[d].z = L.z * L.z; S[d].w = L.w * L.w;
    }

    const float y = ys[b];

    // MC term: each 16-lane group handles one k per iteration; 16 groups/block,
    // 2 iterations -> all 32 k. fs replicated across the 16 lanes after the
    // butterfly, so scale the accumulated lp by 1/16.
    float lp_acc = 0.0f;
#pragma unroll
    for (int i = 0; i < 2; ++i) {
        const int k = wave * 4 + ksub + 16 * i;
        const float4* e0 = reinterpret_cast<const float4*>(
            eps + (((size_t)0 * kB + b) * kK1 + k) * kRank);
        const float4* e1 = reinterpret_cast<const float4*>(
            eps + (((size_t)1 * kB + b) * kK1 + k) * kRank);
        const float4* e2 = reinterpret_cast<const float4*>(
            eps + (((size_t)2 * kB + b) * kK1 + k) * kRank);
        const float4 ea = e0[rg];
        const float4 eb = e1[rg];
        const float4 ec = e2[rg];

        float4 t0, t1, t2;
        t0.x = fmaf(ea.x, S[0].x, m[0].x); t0.y = fmaf(ea.y, S[0].y, m[0].y);
        t0.z = fmaf(ea.z, S[0].z, m[0].z); t0.w = fmaf(ea.w, S[0].w, m[0].w);
        t1.x = fmaf(eb.x, S[1].x, m[1].x); t1.y = fmaf(eb.y, S[1].y, m[1].y);
        t1.z = fmaf(eb.z, S[1].z, m[1].z); t1.w = fmaf(eb.w, S[1].w, m[1].w);
        t2.x = fmaf(ec.x, S[2].x, m[2].x); t2.y = fmaf(ec.y, S[2].y, m[2].y);
        t2.z = fmaf(ec.z, S[2].z, m[2].z); t2.w = fmaf(ec.w, S[2].w, m[2].w);

        float part = (t0.x * t1.x * t2.x + t0.y * t1.y * t2.y) +
                     (t0.z * t1.z * t2.z + t0.w * t1.w * t2.w);
        // Reduce over the 16 lanes of this k-group (ranks 0..63).
        part += __shfl_xor(part, 1, 64);
        part += __shfl_xor(part, 2, 64);
        part += __shfl_xor(part, 4, 64);
        part += __shfl_xor(part, 8, 64);

        const float diff = part - y;
        lp_acc += -0.5f * diff * diff - kHalfLog2Pi;
    }

    float v = -(100.0f / 32.0f) * (lp_acc * (1.0f / 16.0f));

    // KL: only threads 0..15 (they jointly hold all 64 ranks, once).
    if (tid < 16) {
        float klsum = 0.0f;
#pragma unroll
        for (int d = 0; d < kNDim; ++d) {
            const float4 s = S[d];
            const float4 mm = m[d];
            float4 s2;
            s2.x = s.x * s.x; s2.y = s.y * s.y;
            s2.z = s.z * s.z; s2.w = s.w * s.w;
            klsum += 0.5f * (s2.x + mm.x * mm.x - 1.0f - __logf(s2.x));
            klsum += 0.5f * (s2.y + mm.y * mm.y - 1.0f - __logf(s2.y));
            klsum += 0.5f * (s2.z + mm.z * mm.z - 1.0f - __logf(s2.z));
            klsum += 0.5f * (s2.w + mm.w * mm.w - 1.0f - __logf(s2.w));
        }
        v += klsum * (1.0f / 8192.0f);
    }

    // Block reduction: wave butterfly then LDS across 4 waves.
#pragma unroll
    for (int off = 32; off >= 1; off >>= 1) v += __shfl_down(v, off, 64);

    __shared__ float red[4];
    if (lane == 0) red[wave] = v;
    __syncthreads();
    if (tid == 0) {
        partials[b] = (red[0] + red[1]) + (red[2] + red[3]);
    }
}

// One block sums the 8192 per-b partials -> out[0]. Deterministic, no atomics.
__global__ __launch_bounds__(256) void ssvi_reduce_kernel(
    const float* __restrict__ partials, float* __restrict__ out)
{
    const int tid  = threadIdx.x;
    const int lane = tid & 63;
    const int wave = tid >> 6;
    float v = 0.0f;
#pragma unroll
    for (int i = 0; i < kB / 256; ++i) v += partials[tid + i * 256];
#pragma unroll
    for (int off = 32; off >= 1; off >>= 1) v += __shfl_down(v, off, 64);
    __shared__ float red[4];
    if (lane == 0) red[wave] = v;
    __syncthreads();
    if (tid == 0) out[0] = (red[0] + red[1]) + (red[2] + red[3]);
}

extern "C" void kernel_launch(void* const* d_in, const int* in_sizes, int n_in,
                              void* d_out, int out_size, void* d_ws, size_t ws_size,
                              hipStream_t stream) {
    const int*   entries = (const int*)d_in[0];
    const float* ys      = (const float*)d_in[1];
    const float* means   = (const float*)d_in[2];
    const float* chols   = (const float*)d_in[3];
    const float* eps     = (const float*)d_in[4];
    float* out      = (float*)d_out;
    float* partials = (float*)d_ws;  // 8192 floats = 32 KB of the workspace

    ssvi_partial_kernel<<<kB, 256, 0, stream>>>(entries, ys, means, chols, eps,
                                                partials);
    ssvi_reduce_kernel<<<1, 256, 0, stream>>>(partials, out);
}